// Round 10
// baseline (157.141 us; speedup 1.0000x reference)
//
#include <hip/hip_runtime.h>
#include <math.h>

// Problem constants (from reference setup_inputs)
#define BATCH 512
#define LEN   16384
#define WIN   5
#define WOUT  (LEN - WIN + 1)   // 16380
#define TPB   256
#define WPT   4                  // windows per thread (WOUT % WPT == 0)
#define WPB   (TPB * WPT)        // 1024 windows per block
#define EPT   (WPT + WIN - 1)    // 8 elements per thread
#define WBLKS ((WOUT + WPB - 1) / WPB)   // 16 window-column blocks
#define RWGS  ((WOUT + TPB - 1) / TPB)   // 64 reduce blocks

// LDS tile layout (per buffer), identical to the verified r9 body:
// [mask @0 (4112 used)][tgt @5120 (4112 used)][pred @10240 (8224 used)]
#define LBUF   19456

// fast reciprocal: v_rcp_f32 + 1 Newton step, ~3 insts vs ~10 for fdiv
__device__ __forceinline__ float fast_rcp(float x) {
    float r = __builtin_amdgcn_rcpf(x);
    return r * fmaf(-x, r, 2.0f);
}

__device__ __forceinline__ void gload16(const char* src, char* dst) {
    __builtin_amdgcn_global_load_lds(
        (const __attribute__((address_space(1))) unsigned int*)src,
        (__attribute__((address_space(3))) unsigned int*)dst,
        16, 0, 0);
}

struct RowRaw {
    int4   m0, m1, t0, t1;
    float4 q0, q1, q2, q3;
};
struct RowArr {
    float m[EPT], tm[EPT], pm[EPT], p2m[EPT];
};

// Same per-element arithmetic as all previously-verified rounds.
__device__ __forceinline__ RowArr convert_row(const RowRaw& r) {
    RowArr a;
    const int mi[EPT] = {r.m0.x, r.m0.y, r.m0.z, r.m0.w,
                         r.m1.x, r.m1.y, r.m1.z, r.m1.w};
    const int ti[EPT] = {r.t0.x, r.t0.y, r.t0.z, r.t0.w,
                         r.t1.x, r.t1.y, r.t1.z, r.t1.w};
    const float dx[EPT] = {r.q0.x - r.q0.y, r.q0.z - r.q0.w,
                           r.q1.x - r.q1.y, r.q1.z - r.q1.w,
                           r.q2.x - r.q2.y, r.q2.z - r.q2.w,
                           r.q3.x - r.q3.y, r.q3.z - r.q3.w};
#pragma unroll
    for (int i = 0; i < EPT; ++i) {
        const float p  = fast_rcp(1.0f + __expf(dx[i]));  // softmax[...,1]
        const float mf = (float)mi[i];
        a.m[i]   = mf;
        a.tm[i]  = (float)(ti[i] & mi[i]);  // t*m, both in {0,1}
        a.pm[i]  = p * mf;
        a.p2m[i] = p * p * mf;
    }
    return a;
}

// Same window math & ascending tap order -> bit-identical partials.
__device__ __forceinline__ void windows_row(const RowArr& a,
                                            float accd2[WPT], float accms[WPT]) {
#pragma unroll
    for (int w = 0; w < WPT; ++w) {
        float msum = 0.f, stm = 0.f, spm = 0.f, sp2m = 0.f;
#pragma unroll
        for (int k = 0; k < WIN; ++k) {
            msum += a.m[w + k];
            stm  += a.tm[w + k];
            spm  += a.pm[w + k];
            sp2m += a.p2m[w + k];
        }
        // st2m == stm since t in {0,1}
        const float denom = fmaxf(msum, 1.0f);
        const float inv   = fast_rcp(denom);
        const float pmean = spm * inv;
        const float tmean = stm * inv;
        const float pvar  = (sp2m - 2.0f * pmean * spm + pmean * pmean * msum) * inv;
        const float tvar  = (stm  - 2.0f * tmean * stm + tmean * tmean * msum) * inv;
        const float d = pvar - tvar;
        accd2[w] += d * d;
        accms[w] += msum;
    }
}

// Kernel 1: r9's verified exact-size LDS-DMA staging, restructured as a
// DEPTH-3 pipeline with COUNTED vmcnt -- loads are never drained to 0 in
// the main loop (the one structure all ten prior rounds lacked; T3/T4
// counted-vmcnt is +38-73% on GEMM for exactly this reason). Per iteration:
// issue stage(it+2) -> compute(cur=it) -> vmcnt(4) (stage(it+1) fully
// landed, stage(it+2) still in flight) -> RAW s_barrier (NOT __syncthreads,
// which re-inserts the vmcnt(0) drain) -> rotate. Per-wave issue counts
// are 5,5,5,4 (col<15) / 4,4,4,4 (col 15), so vmcnt(4) is the universal
// safe constant. sched_barrier(0) fences stop compute migrating across
// the wait (rule #18).
__global__ __launch_bounds__(TPB)
void bcl_partial_staged(const float* __restrict__ pred,
                        const int*   __restrict__ tgt,
                        const int*   __restrict__ msk,
                        float* __restrict__ part_d2,
                        float* __restrict__ part_ms,
                        double* __restrict__ accum,
                        unsigned int* __restrict__ ticket,
                        int bper) {
    __shared__ __align__(1024) char s_lds[3 * LBUF];
    const int col   = blockIdx.x;          // 0..WBLKS-1
    const int chunk = blockIdx.y;
    const int tid   = (int)threadIdx.x;
    const int lane  = tid & 63, wid = tid >> 6;
    const int j0    = col * WPB + tid * WPT;   // first window owned
    const int b0    = chunk * bper;

    // zero global accumulators for the reduce kernel (ws re-poisoned per call)
    if (col == 0 && chunk == 0 && tid == 0) {
        accum[0] = 0.0; accum[1] = 0.0; *ticket = 0u;
    }

    const char* mbytes = (const char*)msk;
    const char* tbytes = (const char*)tgt;
    const char* pbytes = (const char*)pred;
    const int cmt = col * (WPB * 4);   // mask/tgt tile byte offset in row
    const int cpr = col * (WPB * 8);   // pred tile byte offset in row
    // Tail-issue validity: col<15 tiles need 1028 elements; col=15 ends at
    // the row boundary and no valid thread reads past element 1023 there.
    const bool mt_tail = (cmt + 4112 <= LEN * 4);
    const bool pr_tail = (cpr + 8224 <= LEN * 8);

    // Stage one batch-row's tile into LDS buffer `buf` (identical to r9).
    // Full issues: 1KB (64 lanes x 16B), 4 per wave. Tails: exec-masked
    // 16/32B issues on waves 0-2 (verified absmax=0 in r9).
    auto stage = [&](char* buf, int b) {
        const char* mrow = mbytes + (size_t)b * (LEN * 4);
        const char* trow = tbytes + (size_t)b * (LEN * 4);
        const char* prow = pbytes + (size_t)b * (LEN * 8);
#pragma unroll
        for (int u = 0; u < 4; ++u) {          // i = wid + 4u: 4 issues/wave
            const int i = wid + 4 * u;
            const char* src; char* dst;
            if (i < 4) {                       // mask: 4 x 1KB
                src = mrow + cmt + (i << 10);          dst = buf + (i << 10);
            } else if (i < 8) {                // tgt: 4 x 1KB
                const int k = i - 4;
                src = trow + cmt + (k << 10);          dst = buf + 5120 + (k << 10);
            } else {                           // pred: 8 x 1KB
                const int k = i - 8;
                src = prow + cpr + (k << 10);          dst = buf + 10240 + (k << 10);
            }
            gload16(src + lane * 16, dst);
        }
        // exact tails: mask 4096..4112, tgt 4096..4112, pred 8192..8224
        if (wid == 0 && lane == 0 && mt_tail)
            gload16(mrow + cmt + 4096, buf + 4096);
        if (wid == 1 && lane == 0 && mt_tail)
            gload16(trow + cmt + 4096, buf + 5120 + 4096);
        if (wid == 2 && lane < 2 && pr_tail)
            gload16(prow + cpr + 8192 + lane * 16, buf + 10240 + 8192);
    };

    char* pA = s_lds;
    char* pB = s_lds + LBUF;
    char* pC = s_lds + 2 * LBUF;

    float accd2[WPT] = {0.f, 0.f, 0.f, 0.f};
    float accms[WPT] = {0.f, 0.f, 0.f, 0.f};

    // prologue: rows b0, b0+1 in flight; wait only for row b0 (vmcnt(4)
    // leaves row b0+1's issues outstanding).  bper = 16 >= 2 always.
    stage(pA, b0);
    stage(pB, b0 + 1);
    asm volatile("s_waitcnt vmcnt(4)" ::: "memory");
    __builtin_amdgcn_s_barrier();
    __builtin_amdgcn_sched_barrier(0);

    char* cur = pA; char* nxt = pB; char* fre = pC;

    for (int it = 0; it < bper; ++it) {      // ascending b: deterministic
        if (it + 2 < bper) stage(fre, b0 + it + 2);   // 2-ahead prefetch

        if (j0 < WOUT) {   // only col=WBLKS-1/tid=255 is ever excluded
            RowRaw r;
            const int e0 = tid << 4;                   // 4 elems * 4B stride
            r.m0 = *(const int4*)(cur + e0);
            r.m1 = *(const int4*)(cur + e0 + 16);
            r.t0 = *(const int4*)(cur + 5120 + e0);
            r.t1 = *(const int4*)(cur + 5120 + e0 + 16);
            const int p0 = 10240 + (tid << 5);         // 4 elems * 8B stride
            r.q0 = *(const float4*)(cur + p0);
            r.q1 = *(const float4*)(cur + p0 + 16);
            r.q2 = *(const float4*)(cur + p0 + 32);
            r.q3 = *(const float4*)(cur + p0 + 48);
            RowArr a = convert_row(r);
            windows_row(a, accd2, accms);
        }

        __builtin_amdgcn_sched_barrier(0);   // pin compute before the wait
        if (it + 2 < bper) {
            // stage(it+1) fully landed; stage(it+2) stays in flight
            asm volatile("s_waitcnt vmcnt(4)" ::: "memory");
        } else if (it + 1 < bper) {
            asm volatile("s_waitcnt vmcnt(0)" ::: "memory");  // final drain
        }
        __builtin_amdgcn_s_barrier();        // raw: no implicit vmcnt(0)
        __builtin_amdgcn_sched_barrier(0);   // nothing hoists above it

        char* t = cur; cur = nxt; nxt = fre; fre = t;   // rotate 3 buffers
    }

    if (j0 < WOUT) {
        *(float4*)(part_d2 + (size_t)chunk * WOUT + j0) =
            make_float4(accd2[0], accd2[1], accd2[2], accd2[3]);
        *(float4*)(part_ms + (size_t)chunk * WOUT + j0) =
            make_float4(accms[0], accms[1], accms[2], accms[3]);
    }
}

// Kernel 2: single direct reduce (r7/r9-verified). 64 WGs fold the chunks
// per window (ascending c), gate ms>0, block-reduce to doubles, atomicAdd,
// last block finalizes.
__global__ __launch_bounds__(TPB)
void bcl_window_reduce(const float* __restrict__ part_d2,
                       const float* __restrict__ part_ms,
                       double* __restrict__ accum,   // [num, cnt]
                       unsigned int* __restrict__ ticket,
                       float* __restrict__ out,
                       int nchunks) {
    const int j = blockIdx.x * blockDim.x + threadIdx.x;
    double num = 0.0, cnt = 0.0;
    if (j < WOUT) {
        float d2 = 0.f, ms = 0.f;
#pragma unroll 8
        for (int c = 0; c < nchunks; ++c) {   // ascending c: deterministic
            d2 += part_d2[(size_t)c * WOUT + j];
            ms += part_ms[(size_t)c * WOUT + j];
        }
        if (ms > 0.f) {
            num = (double)d2 * (1.0 / (double)BATCH);
            cnt = 1.0;
        }
    }
    // wave reduce (wave = 64)
    for (int off = 32; off > 0; off >>= 1) {
        num += __shfl_down(num, off, 64);
        cnt += __shfl_down(cnt, off, 64);
    }
    __shared__ double s_num[4], s_cnt[4];
    const int lane = threadIdx.x & 63, wave = threadIdx.x >> 6;
    if (lane == 0) { s_num[wave] = num; s_cnt[wave] = cnt; }
    __syncthreads();
    if (threadIdx.x == 0) {
        double n = 0.0, c = 0.0;
        for (int wv = 0; wv < TPB / 64; ++wv) { n += s_num[wv]; c += s_cnt[wv]; }
        atomicAdd(&accum[0], n);
        atomicAdd(&accum[1], c);
        __threadfence();
        const unsigned int t = atomicAdd(ticket, 1u);
        if (t == gridDim.x - 1) {
            out[0] = (float)(accum[0] / fmax(accum[1], 1.0));
        }
    }
}

extern "C" void kernel_launch(void* const* d_in, const int* in_sizes, int n_in,
                              void* d_out, int out_size, void* d_ws, size_t ws_size,
                              hipStream_t stream) {
    const float* pred = (const float*)d_in[0];
    const int*   tgt  = (const int*)d_in[1];
    const int*   msk  = (const int*)d_in[2];
    float* out = (float*)d_out;

    // nchunks = 32 -> grid (16,32) = 512 WGs, bper = 16 (r9-verified config).
    int nchunks = 32;
    while (nchunks > 2) {
        size_t need = (size_t)nchunks * WOUT * 2 * sizeof(float) + 256;
        if (need <= ws_size) break;
        nchunks >>= 1;
    }
    const int bper = BATCH / nchunks;

    float* part_d2 = (float*)d_ws;
    float* part_ms = part_d2 + (size_t)nchunks * WOUT;
    // 16-byte-aligned tail region: [double num, double cnt, uint ticket]
    size_t off = ((size_t)((char*)(part_ms + (size_t)nchunks * WOUT) - (char*)d_ws) + 15) & ~(size_t)15;
    double* accum = (double*)((char*)d_ws + off);
    unsigned int* ticket = (unsigned int*)(accum + 2);

    dim3 g1(WBLKS, nchunks);   // 16 x 32 = 512 WGs
    bcl_partial_staged<<<g1, TPB, 0, stream>>>(pred, tgt, msk, part_d2, part_ms,
                                               accum, ticket, bper);

    bcl_window_reduce<<<RWGS, TPB, 0, stream>>>(part_d2, part_ms, accum, ticket,
                                                out, nchunks);
}